// Round 10
// baseline (283.604 us; speedup 1.0000x reference)
//
#include <hip/hip_runtime.h>
#include <hip/hip_bf16.h>
#include <math.h>
#include <stdint.h>

// Problem constants (B=2, S=2048 -> T=4096 tokens)
#define TOKENS 4096
#define HDIM   768
#define FFDIM  1536
#define NEXP   8
#define NCT    12     // col tiles: GEMM1 1536/128, GEMM2 768/64 (same count!)
#define GEMM_GRID 768 // 96 blocks per bucket; id%8 = bucket -> XCD affinity

typedef __attribute__((ext_vector_type(8))) short bf16x8;   // 8 bf16 = 4 VGPRs
typedef __attribute__((ext_vector_type(4))) float f32x4;    // MFMA accumulator

// round-to-nearest-even f32 -> bf16 (bit pattern)
__device__ __forceinline__ unsigned short f2bf(float f) {
    union { float f; uint32_t u; } c; c.f = f;
    uint32_t u = c.u;
    uint32_t r = (u + 0x7FFFu + ((u >> 16) & 1u)) >> 16;
    return (unsigned short)r;
}

// 8x fp32 -> 8x bf16 (RNE, packed cvt)
__device__ __forceinline__ bf16x8 cvt8(float4 a, float4 b) {
    union { bf16x8 v; __hip_bfloat162 p[4]; } u;
    u.p[0] = __float22bfloat162_rn(make_float2(a.x, a.y));
    u.p[1] = __float22bfloat162_rn(make_float2(a.z, a.w));
    u.p[2] = __float22bfloat162_rn(make_float2(b.x, b.y));
    u.p[3] = __float22bfloat162_rn(make_float2(b.z, b.w));
    return u.v;
}

// ---------------------------------------------------------------------------
// Gating: one wave per token (4 tokens / 256-thread block). fp32 logits
// (checked output!), top-2 softmax, no atomics. Fused: bf16 cast of x, and
// zeroing of outp (must precede GEMM2, which is stream-ordered after).
__global__ __launch_bounds__(256) void gating(
    const float* __restrict__ x, const float* __restrict__ gw,
    float* __restrict__ logits,
    int* __restrict__ tok_e, float* __restrict__ tok_g,
    unsigned short* __restrict__ x_bf, float* __restrict__ outp)
{
    // zero outp: 786432 float4 over 1024 blocks = 3 per thread
    float4 zz = make_float4(0.f, 0.f, 0.f, 0.f);
#pragma unroll
    for (int j = 0; j < 3; j++)
        ((float4*)outp)[blockIdx.x * 768 + j * 256 + threadIdx.x] = zz;

    int t = blockIdx.x * 4 + (threadIdx.x >> 6);
    int lane = threadIdx.x & 63;
    const float4* xt = (const float4*)(x + (size_t)t * HDIM);   // 192 float4/token
    const float4* gw4 = (const float4*)gw;                      // [E][192]
    ushort4* xbt = (ushort4*)(x_bf + (size_t)t * HDIM);
    float acc[NEXP];
#pragma unroll
    for (int e = 0; e < NEXP; e++) acc[e] = 0.f;
#pragma unroll
    for (int it = 0; it < 3; it++) {
        int i = lane + it * 64;
        float4 xv = xt[i];
        ushort4 o;
        o.x = f2bf(xv.x); o.y = f2bf(xv.y); o.z = f2bf(xv.z); o.w = f2bf(xv.w);
        xbt[i] = o;
#pragma unroll
        for (int e = 0; e < NEXP; e++) {
            float4 wv = gw4[e * 192 + i];
            acc[e] += xv.x * wv.x + xv.y * wv.y + xv.z * wv.z + xv.w * wv.w;
        }
    }
#pragma unroll
    for (int e = 0; e < NEXP; e++) {
#pragma unroll
        for (int off = 32; off > 0; off >>= 1)
            acc[e] += __shfl_xor(acc[e], off);
    }
    if (lane == 0) {
        float4 l0 = make_float4(acc[0], acc[1], acc[2], acc[3]);
        float4 l1 = make_float4(acc[4], acc[5], acc[6], acc[7]);
        float4* lp = (float4*)(logits + (size_t)t * NEXP);
        lp[0] = l0; lp[1] = l1;
        int i0 = 0; float v0 = acc[0];
#pragma unroll
        for (int e = 1; e < NEXP; e++) if (acc[e] > v0) { v0 = acc[e]; i0 = e; }
        int i1 = -1; float v1 = -3.4e38f;
#pragma unroll
        for (int e = 0; e < NEXP; e++) if (e != i0 && acc[e] > v1) { v1 = acc[e]; i1 = e; }
        float g0 = 1.f / (1.f + expf(v1 - v0));   // softmax over top-2 (v0 >= v1)
        tok_e[t * 2] = i0; tok_e[t * 2 + 1] = i1;
        tok_g[t * 2] = g0; tok_g[t * 2 + 1] = 1.f - g0;
    }
}

// ---------------------------------------------------------------------------
// Build per-expert routed lists deterministically (no global atomics).
// Single block, 1024 threads (16 waves), 8 (token,k) entries per thread.
// Per-wave __shfl_up u64 scan + 16-wave fixup. Work table (XCD-aware):
// bucket b == expert e; slot p of bucket b at work[p*8+b]; fill[b] =
// rts_e * NCT. Table written IN PARALLEL by 96 threads (one per (e,ct)).
__global__ __launch_bounds__(1024) void build_lists(
    const int* __restrict__ tok_e, const float* __restrict__ tok_g,
    int* __restrict__ counts, int* __restrict__ bases, int* __restrict__ fill,
    int* __restrict__ work,
    int* __restrict__ entries, float* __restrict__ gates)
{
    __shared__ unsigned long long wlo[16], whi[16];
    __shared__ int scnt[8];
    int tid = threadIdx.x;
    int lane = tid & 63, wid = tid >> 6;

    int eL[8]; float gL[8];
    int4 ea = ((const int4*)tok_e)[tid * 2];
    int4 eb = ((const int4*)tok_e)[tid * 2 + 1];
    float4 ga = ((const float4*)tok_g)[tid * 2];
    float4 gb = ((const float4*)tok_g)[tid * 2 + 1];
    eL[0] = ea.x; eL[1] = ea.y; eL[2] = ea.z; eL[3] = ea.w;
    eL[4] = eb.x; eL[5] = eb.y; eL[6] = eb.z; eL[7] = eb.w;
    gL[0] = ga.x; gL[1] = ga.y; gL[2] = ga.z; gL[3] = ga.w;
    gL[4] = gb.x; gL[5] = gb.y; gL[6] = gb.z; gL[7] = gb.w;

    unsigned long long clo = 0, chi = 0;
#pragma unroll
    for (int j = 0; j < 8; j++) {
        int e = eL[j];
        unsigned long long one = 1ull << ((e & 3) * 16);
        if (e < 4) clo += one; else chi += one;
    }
    unsigned long long ilo = clo, ihi = chi;
#pragma unroll
    for (int s = 1; s < 64; s <<= 1) {
        unsigned long long t1 = __shfl_up(ilo, s);
        unsigned long long t2 = __shfl_up(ihi, s);
        if (lane >= s) { ilo += t1; ihi += t2; }
    }
    if (lane == 63) { wlo[wid] = ilo; whi[wid] = ihi; }
    __syncthreads();
    if (tid == 0) {
        unsigned long long rl = 0, rh = 0;
#pragma unroll
        for (int i = 0; i < 16; i++) {
            unsigned long long a = wlo[i], b = whi[i];
            wlo[i] = rl; whi[i] = rh;   // exclusive wave prefix
            rl += a; rh += b;
        }
        int c[8];
#pragma unroll
        for (int e = 0; e < 4; e++) {
            c[e]     = (int)((rl >> (e * 16)) & 0xFFFF);
            c[e + 4] = (int)((rh >> (e * 16)) & 0xFFFF);
        }
        int b = 0;
#pragma unroll
        for (int e = 0; e < NEXP; e++) {
            scnt[e] = c[e]; counts[e] = c[e]; bases[e] = b; b += c[e];
            fill[e] = ((c[e] + 127) >> 7) * NCT;
        }
    }
    __syncthreads();
    // parallel work-table writers: thread (e, ct), e=tid/12, ct=tid%12
    if (tid < NEXP * NCT) {
        int e = tid / NCT, ct = tid % NCT;
        int rts = (scnt[e] + 127) >> 7;
        for (int r = 0; r < rts; r++)
            work[(ct * rts + r) * 8 + e] = (ct << 20) | (e << 16) | (r << 7);
    }
    unsigned long long rlo = wlo[wid] + (ilo - clo);   // exclusive thread prefix
    unsigned long long rhi = whi[wid] + (ihi - chi);
#pragma unroll
    for (int j = 0; j < 8; j++) {
        int e = eL[j];
        int sh = (e & 3) * 16;
        unsigned long long one = 1ull << sh;
        int slot;
        if (e < 4) { slot = (int)((rlo >> sh) & 0xFFFF); rlo += one; }
        else       { slot = (int)((rhi >> sh) & 0xFFFF); rhi += one; }
        entries[e * TOKENS + slot] = tid * 8 + j;   // = t*2+k
        gates[e * TOKENS + slot]   = gL[j];
    }
}

// ---------------------------------------------------------------------------
// Routed GEMM, 128xTN tile, BK=64, REGISTER-PREFETCH PIPELINE.
// KEY STRUCTURAL CHANGE (r5/r9 dbuf failures + guide m131-m141): NO
// global_load_lds anywhere — any in-flight load_lds forces vmcnt(0) at every
// s_barrier, serializing the loop. Staging is plain global loads -> VGPRs
// (barriers don't drain those) -> ds_write. Two register sets, 2x-unrolled:
// loads for step k+1 are issued before ds_write/compute of step k, so their
// ~200-900 cyc latency overlaps MFMA. B is read DIRECTLY AS FP32 (packed
// cvt in the round-trip) — the 113 MB cast_bf16_2 pass is deleted.
// LDS rows 128B (8x16B segs), seg^(row&7): ds_read_b128 conflict-free
// (verified r6/r8); ds_write pattern gives each 4-bank group exactly 8
// lanes/instr (balanced, free). 4 waves in 2x2.
// PERSISTENT blocks: bucket b = blockIdx.x%8 (= expert, XCD-affine; verified
// r8: FETCH 122 -> 25 MB); block strides slots p = blockIdx.x/8, +96.
//   IS_FC:  A = x_bf gathered via entry list (row = entry>>1), out = gelu ->
//           hmid[base[e]+slot][ND] (slot-compacted, so GEMM2 reads it dense)
//   !IS_FC: A = hmid[base[e]+row] contiguous, out = atomicAdd(gate * acc)
template<int KD, int ND, int TN, bool IS_FC>
__global__ __launch_bounds__(256) void moe_gemm(
    const unsigned short* __restrict__ Asrc,    // bf16 activations
    const float* __restrict__ Bsrc,             // [E][ND][KD] fp32 weights (B^T)
    const int* __restrict__ counts,
    const int* __restrict__ bases,
    const int* __restrict__ fill,
    const int* __restrict__ work,
    const int* __restrict__ entries,
    const float* __restrict__ gates,
    unsigned short* __restrict__ hmid,
    float* __restrict__ outp)
{
    constexpr int AJ   = TN / 32;      // col frags per wave (4 or 2)
    constexpr int BSEG = TN / 32;      // B 16B-segs per thread per K-step
    int bkt = blockIdx.x & 7;
    int nfill = fill[bkt];

    int tid = threadIdx.x;
    int w = tid >> 6;          // wave 0..3
    int l = tid & 63;          // lane
    int gs  = tid & 7;         // this thread's fixed global K-seg (16B)
    int rg  = tid >> 3;        // row group 0..31
    int lo = l & 15;
    int q  = l >> 4;
    int wr = w >> 1, wc = w & 1;

    __shared__ __align__(16) unsigned short sA[128 * 64];
    __shared__ __align__(16) unsigned short sB[TN * 64];

    // fragment LDS offsets: sub-step s reads K-seg s*4+q of row m at stored
    // seg (s*4+q)^(m&7)  [r8 layout — 0 conflicts measured]
    int aOff[4][2], bOff[AJ][2];
#pragma unroll
    for (int i = 0; i < 4; i++) {
        int m = wr * 64 + i * 16 + lo;
#pragma unroll
        for (int s = 0; s < 2; s++)
            aOff[i][s] = m * 64 + ((s * 4 + q) ^ (m & 7)) * 8;
    }
#pragma unroll
    for (int j = 0; j < AJ; j++) {
        int n = wc * (TN / 2) + j * 16 + lo;
#pragma unroll
        for (int s = 0; s < 2; s++)
            bOff[j][s] = n * 64 + ((s * 4 + q) ^ (n & 7)) * 8;
    }

#define LOADR(st, kk)                                                         \
    {                                                                         \
        _Pragma("unroll")                                                     \
        for (int c = 0; c < 4; c++) rA[st][c] = *(const bf16x8*)(Ap[c] + (kk)); \
        _Pragma("unroll")                                                     \
        for (int c = 0; c < BSEG; c++) {                                      \
            rB[st][c][0] = *(const float4*)(Bp[c] + (kk));                    \
            rB[st][c][1] = *(const float4*)(Bp[c] + (kk) + 4);                \
        }                                                                     \
    }
#define WRITE(st)                                                             \
    {                                                                         \
        _Pragma("unroll")                                                     \
        for (int c = 0; c < 4; c++) *(bf16x8*)(sA + aW[c]) = rA[st][c];       \
        _Pragma("unroll")                                                     \
        for (int c = 0; c < BSEG; c++)                                        \
            *(bf16x8*)(sB + bW[c]) = cvt8(rB[st][c][0], rB[st][c][1]);        \
    }
#define COMPUTE                                                               \
    {                                                                         \
        _Pragma("unroll")                                                     \
        for (int s = 0; s < 2; s++) {                                         \
            bf16x8 a[4], b[AJ];                                               \
            _Pragma("unroll")                                                 \
            for (int i = 0; i < 4; i++) a[i] = *(const bf16x8*)(sA + aOff[i][s]); \
            _Pragma("unroll")                                                 \
            for (int j = 0; j < AJ; j++) b[j] = *(const bf16x8*)(sB + bOff[j][s]); \
            _Pragma("unroll")                                                 \
            for (int i = 0; i < 4; i++)                                       \
                _Pragma("unroll")                                             \
                for (int j = 0; j < AJ; j++)                                  \
                    acc[i][j] = __builtin_amdgcn_mfma_f32_16x16x32_bf16(      \
                        a[i], b[j], acc[i][j], 0, 0, 0);                      \
        }                                                                     \
    }

    for (int p = blockIdx.x >> 3; p < nfill; p += GEMM_GRID / 8) {
        int pk   = work[p * 8 + bkt];
        int ct   = pk >> 20;
        int e    = (pk >> 16) & 0xF;
        int row0 = pk & 0xFFFF;
        int n_e  = counts[e];
        int ebase = bases[e];
        int n0 = ct * TN;
        const int* lst = entries + e * TOKENS;

        // ---- staging addresses. Thread owns global K-seg gs of 4 A rows
        // (rg*4+c) and BSEG B rows (rg*BSEG+c). LDS dest seg = gs^(row&7).
        const unsigned short* Ap[4]; int aW[4];
#pragma unroll
        for (int c = 0; c < 4; c++) {
            int rr = rg * 4 + c;
            int gr = row0 + rr;
            int id = gr < n_e ? gr : n_e - 1;    // clamp (discarded in epilogue)
            size_t arow = IS_FC ? (size_t)(lst[id] >> 1) : (size_t)(ebase + id);
            Ap[c] = Asrc + arow * KD + gs * 8;
            aW[c] = rr * 64 + (gs ^ (rr & 7)) * 8;
        }
        const float* Bp[BSEG]; int bW[BSEG];
#pragma unroll
        for (int c = 0; c < BSEG; c++) {
            int rr = rg * BSEG + c;
            Bp[c] = Bsrc + ((size_t)e * ND + n0 + rr) * KD + gs * 8;
            bW[c] = rr * 64 + (gs ^ (rr & 7)) * 8;
        }

        f32x4 acc[4][AJ];
#pragma unroll
        for (int i = 0; i < 4; i++)
#pragma unroll
            for (int j = 0; j < AJ; j++) acc[i][j] = (f32x4){0.f, 0.f, 0.f, 0.f};

        bf16x8 rA[2][4];
        float4 rB[2][BSEG][2];

        // ---- pipelined K-loop (2x unrolled, register double-buffer):
        // loads for the NEXT 64-K chunk are in flight across the barriers
        // (they target VGPRs -> no vmcnt drain at s_barrier).
        LOADR(0, 0);
        for (int k0 = 0; k0 < KD; k0 += 128) {
            if (k0 + 64 < KD) LOADR(1, k0 + 64);
            WRITE(0);
            __syncthreads();
            COMPUTE;
            __syncthreads();
            if (k0 + 128 < KD) LOADR(0, k0 + 128);
            WRITE(1);
            __syncthreads();
            COMPUTE;
            __syncthreads();
        }

        // ---- epilogue (D: col=lo, row=q*4+rr)
#pragma unroll
        for (int i = 0; i < 4; i++) {
            int rowB = row0 + wr * 64 + i * 16 + q * 4;
#pragma unroll
            for (int rr = 0; rr < 4; rr++) {
                int orow = rowB + rr;
                if (orow < n_e) {
                    if (IS_FC) {
                        size_t hrow = (size_t)(ebase + orow);
#pragma unroll
                        for (int j = 0; j < AJ; j++) {
                            float v = acc[i][j][rr];
                            v = 0.5f * v * (1.f + erff(v * 0.70710678118654752f));  // exact gelu
                            hmid[hrow * ND + n0 + wc * (TN / 2) + j * 16 + lo] = f2bf(v);
                        }
                    } else {
                        int token = lst[orow] >> 1;
                        float g = gates[e * TOKENS + orow];
#pragma unroll
                        for (int j = 0; j < AJ; j++) {
                            atomicAdd(&outp[(size_t)token * ND + n0 + wc * (TN / 2) + j * 16 + lo],
                                      acc[i][j][rr] * g);
                        }
                    }
                }
            }
        }
    }
#undef LOADR
#undef WRITE
#undef COMPUTE
}

// ---------------------------------------------------------------------------
extern "C" void kernel_launch(void* const* d_in, const int* in_sizes, int n_in,
                              void* d_out, int out_size, void* d_ws, size_t ws_size,
                              hipStream_t stream) {
    const float* x     = (const float*)d_in[0];   // [T, H]
    const float* gw    = (const float*)d_in[1];   // [E, H]
    const float* wfc   = (const float*)d_in[2];   // [E, FF, H]
    const float* wproj = (const float*)d_in[3];   // [E, H, FF]
    float* outp   = (float*)d_out;                       // [T*H]
    float* logits = outp + (size_t)TOKENS * HDIM;        // [T*E]

    char* ws = (char*)d_ws;
    int*   counts  = (int*)ws;                            // 8 ints
    int*   bases   = (int*)(ws + 64);                     // 8 ints
    int*   fill    = (int*)(ws + 128);                    // 8 ints
    int*   work    = (int*)(ws + 256);                    // [<=768*8] ints
    size_t off = 256 + (size_t)768 * 8 * 4;
    int*   entries = (int*)(ws + off);                    // [E][T]
    float* gates   = (float*)(ws + off + NEXP * TOKENS * 4);
    off += 2ull * NEXP * TOKENS * 4;
    int*   tok_e   = (int*)(ws + off);   off += (size_t)TOKENS * 2 * 4;
    float* tok_g   = (float*)(ws + off); off += (size_t)TOKENS * 2 * 4;
    unsigned short* x_bf = (unsigned short*)(ws + off); off += (size_t)TOKENS * HDIM * 2;
    unsigned short* hmid = (unsigned short*)(ws + off);  // [2T][FF] bf16, slot-compacted

    gating<<<TOKENS / 4, 256, 0, stream>>>(x, gw, logits, tok_e, tok_g, x_bf, outp);
    build_lists<<<1, 1024, 0, stream>>>(tok_e, tok_g, counts, bases, fill, work,
                                        entries, gates);
    moe_gemm<HDIM, FFDIM, 128, true ><<<GEMM_GRID, 256, 0, stream>>>(
        x_bf, wfc, counts, bases, fill, work, entries, gates, hmid, outp);
    moe_gemm<FFDIM, HDIM, 64, false><<<GEMM_GRID, 256, 0, stream>>>(
        hmid, wproj, counts, bases, fill, work, entries, gates, hmid, outp);
}

// Round 12
// 243.622 us; speedup vs baseline: 1.1641x; 1.1641x over previous
//
#include <hip/hip_runtime.h>
#include <hip/hip_bf16.h>
#include <math.h>
#include <stdint.h>

// Problem constants (B=2, S=2048 -> T=4096 tokens)
#define TOKENS 4096
#define HDIM   768
#define FFDIM  1536
#define NEXP   8
#define NCTA   24     // GEMM1 col tiles (1536/64)
#define NCTB   12     // GEMM2 col tiles (768/64)
#define GEMM_GRID 768 // 96 blocks x 4 waves per bucket; id%8 = bucket -> XCD

typedef __attribute__((ext_vector_type(8))) short bf16x8;   // 8 bf16 = 4 VGPRs
typedef __attribute__((ext_vector_type(4))) float f32x4;    // MFMA accumulator

// round-to-nearest-even f32 -> bf16 (bit pattern)
__device__ __forceinline__ unsigned short f2bf(float f) {
    union { float f; uint32_t u; } c; c.f = f;
    uint32_t u = c.u;
    uint32_t r = (u + 0x7FFFu + ((u >> 16) & 1u)) >> 16;
    return (unsigned short)r;
}

// async global->LDS, 16B per lane; LDS dest is wave-uniform base + lane*16
__device__ __forceinline__ void gload_lds16(const void* g, void* l) {
    __builtin_amdgcn_global_load_lds(
        (const __attribute__((address_space(1))) void*)g,
        (__attribute__((address_space(3))) void*)l, 16, 0, 0);
}

// per-wave drain of outstanding vmem (incl. global_load_lds) WITHOUT a
// block barrier: vmcnt(0), expcnt/lgkmcnt unmasked -> simm16 = 0x0F70.
// The empty asm memory clobber pins subsequent ds_reads after the wait.
__device__ __forceinline__ void wave_vmem_drain() {
    __builtin_amdgcn_s_waitcnt(0x0F70);
    asm volatile("" ::: "memory");
}

// ---------------------------------------------------------------------------
// both weight casts in one dispatch; n4 = float4 count of EACH tensor
__global__ void cast_bf16_2(const float* __restrict__ s1, unsigned short* __restrict__ d1,
                            const float* __restrict__ s2, unsigned short* __restrict__ d2,
                            int n4) {
    int stride = gridDim.x * blockDim.x;
    for (int i = blockIdx.x * blockDim.x + threadIdx.x; i < 2 * n4; i += stride) {
        const float4* s = (i < n4) ? (const float4*)s1 : (const float4*)s2;
        ushort4* d = (i < n4) ? (ushort4*)d1 : (ushort4*)d2;
        int j = (i < n4) ? i : i - n4;
        float4 v = s[j];
        ushort4 o;
        o.x = f2bf(v.x); o.y = f2bf(v.y); o.z = f2bf(v.z); o.w = f2bf(v.w);
        d[j] = o;
    }
}

// ---------------------------------------------------------------------------
// Gating: one wave per token (4 tokens / 256-thread block). fp32 logits
// (checked output!), top-2 softmax, no atomics. Fused: bf16 cast of x, and
// zeroing of outp (must precede GEMM2, which is stream-ordered after).
__global__ __launch_bounds__(256) void gating(
    const float* __restrict__ x, const float* __restrict__ gw,
    float* __restrict__ logits,
    int* __restrict__ tok_e, float* __restrict__ tok_g,
    unsigned short* __restrict__ x_bf, float* __restrict__ outp)
{
    // zero outp: 786432 float4 over 1024 blocks = 3 per thread
    float4 zz = make_float4(0.f, 0.f, 0.f, 0.f);
#pragma unroll
    for (int j = 0; j < 3; j++)
        ((float4*)outp)[blockIdx.x * 768 + j * 256 + threadIdx.x] = zz;

    int t = blockIdx.x * 4 + (threadIdx.x >> 6);
    int lane = threadIdx.x & 63;
    const float4* xt = (const float4*)(x + (size_t)t * HDIM);   // 192 float4/token
    const float4* gw4 = (const float4*)gw;                      // [E][192]
    ushort4* xbt = (ushort4*)(x_bf + (size_t)t * HDIM);
    float acc[NEXP];
#pragma unroll
    for (int e = 0; e < NEXP; e++) acc[e] = 0.f;
#pragma unroll
    for (int it = 0; it < 3; it++) {
        int i = lane + it * 64;
        float4 xv = xt[i];
        ushort4 o;
        o.x = f2bf(xv.x); o.y = f2bf(xv.y); o.z = f2bf(xv.z); o.w = f2bf(xv.w);
        xbt[i] = o;
#pragma unroll
        for (int e = 0; e < NEXP; e++) {
            float4 wv = gw4[e * 192 + i];
            acc[e] += xv.x * wv.x + xv.y * wv.y + xv.z * wv.z + xv.w * wv.w;
        }
    }
#pragma unroll
    for (int e = 0; e < NEXP; e++) {
#pragma unroll
        for (int off = 32; off > 0; off >>= 1)
            acc[e] += __shfl_xor(acc[e], off);
    }
    if (lane == 0) {
        float4 l0 = make_float4(acc[0], acc[1], acc[2], acc[3]);
        float4 l1 = make_float4(acc[4], acc[5], acc[6], acc[7]);
        float4* lp = (float4*)(logits + (size_t)t * NEXP);
        lp[0] = l0; lp[1] = l1;
        int i0 = 0; float v0 = acc[0];
#pragma unroll
        for (int e = 1; e < NEXP; e++) if (acc[e] > v0) { v0 = acc[e]; i0 = e; }
        int i1 = -1; float v1 = -3.4e38f;
#pragma unroll
        for (int e = 0; e < NEXP; e++) if (e != i0 && acc[e] > v1) { v1 = acc[e]; i1 = e; }
        float g0 = 1.f / (1.f + expf(v1 - v0));   // softmax over top-2 (v0 >= v1)
        tok_e[t * 2] = i0; tok_e[t * 2 + 1] = i1;
        tok_g[t * 2] = g0; tok_g[t * 2 + 1] = 1.f - g0;
    }
}

// ---------------------------------------------------------------------------
// Build per-expert routed lists deterministically (no global atomics).
// Single block, 1024 threads (16 waves), 8 (token,k) entries per thread.
// Per-wave __shfl_up u64 scan + 16-wave fixup. Emits TWO XCD-aware work
// tables (64-row tiles): workA (24 col tiles) and workB (12 col tiles);
// bucket b == expert e, slot p at work[p*8+b], fillA/B[b] = rts_e * NCT.
// Tables written IN PARALLEL (one thread per (e,ct) pair).
__global__ __launch_bounds__(1024) void build_lists(
    const int* __restrict__ tok_e, const float* __restrict__ tok_g,
    int* __restrict__ counts, int* __restrict__ bases,
    int* __restrict__ fillA, int* __restrict__ fillB,
    int* __restrict__ workA, int* __restrict__ workB,
    int* __restrict__ entries, float* __restrict__ gates)
{
    __shared__ unsigned long long wlo[16], whi[16];
    __shared__ int scnt[8];
    int tid = threadIdx.x;
    int lane = tid & 63, wid = tid >> 6;

    int eL[8]; float gL[8];
    int4 ea = ((const int4*)tok_e)[tid * 2];
    int4 eb = ((const int4*)tok_e)[tid * 2 + 1];
    float4 ga = ((const float4*)tok_g)[tid * 2];
    float4 gb = ((const float4*)tok_g)[tid * 2 + 1];
    eL[0] = ea.x; eL[1] = ea.y; eL[2] = ea.z; eL[3] = ea.w;
    eL[4] = eb.x; eL[5] = eb.y; eL[6] = eb.z; eL[7] = eb.w;
    gL[0] = ga.x; gL[1] = ga.y; gL[2] = ga.z; gL[3] = ga.w;
    gL[4] = gb.x; gL[5] = gb.y; gL[6] = gb.z; gL[7] = gb.w;

    unsigned long long clo = 0, chi = 0;
#pragma unroll
    for (int j = 0; j < 8; j++) {
        int e = eL[j];
        unsigned long long one = 1ull << ((e & 3) * 16);
        if (e < 4) clo += one; else chi += one;
    }
    unsigned long long ilo = clo, ihi = chi;
#pragma unroll
    for (int s = 1; s < 64; s <<= 1) {
        unsigned long long t1 = __shfl_up(ilo, s);
        unsigned long long t2 = __shfl_up(ihi, s);
        if (lane >= s) { ilo += t1; ihi += t2; }
    }
    if (lane == 63) { wlo[wid] = ilo; whi[wid] = ihi; }
    __syncthreads();
    if (tid == 0) {
        unsigned long long rl = 0, rh = 0;
#pragma unroll
        for (int i = 0; i < 16; i++) {
            unsigned long long a = wlo[i], b = whi[i];
            wlo[i] = rl; whi[i] = rh;   // exclusive wave prefix
            rl += a; rh += b;
        }
        int c[8];
#pragma unroll
        for (int e = 0; e < 4; e++) {
            c[e]     = (int)((rl >> (e * 16)) & 0xFFFF);
            c[e + 4] = (int)((rh >> (e * 16)) & 0xFFFF);
        }
        int b = 0;
#pragma unroll
        for (int e = 0; e < NEXP; e++) {
            scnt[e] = c[e]; counts[e] = c[e]; bases[e] = b; b += c[e];
            int rts = (c[e] + 63) >> 6;
            fillA[e] = rts * NCTA;
            fillB[e] = rts * NCTB;
        }
    }
    __syncthreads();
    // parallel work-table writers (64-row tiles, row0 = r<<6)
    if (tid < NEXP * NCTA) {                       // workA: tid 0..191
        int e = tid / NCTA, ct = tid % NCTA;
        int rts = (scnt[e] + 63) >> 6;
        for (int r = 0; r < rts; r++)
            workA[(ct * rts + r) * 8 + e] = (ct << 20) | (e << 16) | (r << 6);
    }
    if (tid >= 256 && tid < 256 + NEXP * NCTB) {   // workB: tid 256..351
        int t2 = tid - 256;
        int e = t2 / NCTB, ct = t2 % NCTB;
        int rts = (scnt[e] + 63) >> 6;
        for (int r = 0; r < rts; r++)
            workB[(ct * rts + r) * 8 + e] = (ct << 20) | (e << 16) | (r << 6);
    }
    unsigned long long rlo = wlo[wid] + (ilo - clo);   // exclusive thread prefix
    unsigned long long rhi = whi[wid] + (ihi - chi);
#pragma unroll
    for (int j = 0; j < 8; j++) {
        int e = eL[j];
        int sh = (e & 3) * 16;
        unsigned long long one = 1ull << sh;
        int slot;
        if (e < 4) { slot = (int)((rlo >> sh) & 0xFFFF); rlo += one; }
        else       { slot = (int)((rhi >> sh) & 0xFFFF); rhi += one; }
        entries[e * TOKENS + slot] = tid * 8 + j;   // = t*2+k
        gates[e * TOKENS + slot]   = gL[j];
    }
}

// ---------------------------------------------------------------------------
// WAVE-DECOUPLED routed GEMM. Evidence r6 vs r8: duration is insensitive to
// both HBM BW and latency -> the bottleneck was the 4-wave barrier
// rendezvous (2/K-step) + the ~3-coupled-blocks/CU TLP cap. Here EACH WAVE
// owns an independent 64x64-tile job: it stages its own A/B (BK=32, 8x
// global_load_lds) into a private 8 KB LDS quarter, then drains ITS OWN
// vmcnt (s_waitcnt vmcnt(0) — r11's NaN was this wait missing: load_lds has
// no dest reg, so the compiler emits no wait without a barrier), then
// ds_read + 16 MFMA. NO __syncthreads anywhere; ~12 independent wave
// pipelines/CU interleave (m114 co-scheduling). Persistent per-wave item
// loop; bucket = blockIdx%8 (XCD-affine, r8-verified: FETCH 122 -> 25 MB).
// LDS rows 64B, seg swizzle p4^((r>>1)&3): 0 conflicts (measured r2-r4).
//   IS_FC:  A = x_bf gathered via entry list (row = entry>>1), out = gelu ->
//           hmid[base[e]+slot][ND] (slot-compacted, so GEMM2 reads it dense)
//   !IS_FC: A = hmid[base[e]+row] contiguous, out = atomicAdd(gate * acc)
template<int KD, int ND, bool IS_FC>
__global__ __launch_bounds__(256, 3) void moe_gemm(
    const unsigned short* __restrict__ Asrc,
    const unsigned short* __restrict__ Bsrc,    // [E][ND][KD] bf16 (B^T form)
    const int* __restrict__ counts,
    const int* __restrict__ bases,
    const int* __restrict__ fill,
    const int* __restrict__ work,
    const int* __restrict__ entries,
    const float* __restrict__ gates,
    unsigned short* __restrict__ hmid,
    float* __restrict__ outp)
{
    int bkt = blockIdx.x & 7;
    int nfill = fill[bkt];

    int tid = threadIdx.x;
    int w = tid >> 6;          // wave 0..3 (independent jobs!)
    int l = tid & 63;          // lane
    int p4  = l & 3;           // 16B seg within 64B LDS row (staging)
    int lr16 = l >> 2;         // row-within-16 staged by this lane
    int lo = l & 15;
    int q  = l >> 4;

    // 4 private 4 KB quarters each for A and B (no cross-wave sharing)
    __shared__ __align__(16) unsigned short sA[4 * 64 * 32];
    __shared__ __align__(16) unsigned short sB[4 * 64 * 32];
    unsigned short* sAq = sA + w * 2048;
    unsigned short* sBq = sB + w * 2048;

    // fragment LDS offsets (wave-private tile, rows 0..63)
    int aOff[4], bOff[4];
#pragma unroll
    for (int i = 0; i < 4; i++) {
        int m = i * 16 + lo;
        aOff[i] = m * 32 + (q ^ ((m >> 1) & 3)) * 8;
        bOff[i] = aOff[i];                  // same geometry for B
    }

    for (int p = (blockIdx.x >> 3) * 4 + w; p < nfill; p += (GEMM_GRID / 8) * 4) {
        int pk   = work[p * 8 + bkt];
        int ct   = pk >> 20;
        int e    = (pk >> 16) & 0xF;
        int row0 = pk & 0xFFFF;
        int n_e  = counts[e];
        int ebase = bases[e];
        int n0 = ct * 64;
        const int* lst = entries + e * TOKENS;

        // staging addresses: call c covers rows [c*16, c*16+16); lane does
        // row c*16+lr16, global K-seg p4^((row>>1)&3) -> LDS seg p4.
        const unsigned short* Ag[4];
        const unsigned short* Bg[4];
#pragma unroll
        for (int c = 0; c < 4; c++) {
            int rr = c * 16 + lr16;
            int gr = row0 + rr;
            int id = gr < n_e ? gr : n_e - 1;    // clamp (discarded in epilogue)
            size_t arow = IS_FC ? (size_t)(lst[id] >> 1) : (size_t)(ebase + id);
            int gseg = p4 ^ ((rr >> 1) & 3);
            Ag[c] = Asrc + arow * KD + gseg * 8;
            Bg[c] = Bsrc + ((size_t)e * ND + n0 + rr) * KD + gseg * 8;
        }

        f32x4 acc[4][4];
#pragma unroll
        for (int i = 0; i < 4; i++)
#pragma unroll
            for (int j = 0; j < 4; j++) acc[i][j] = (f32x4){0.f, 0.f, 0.f, 0.f};

        // barrier-free K-loop: per-wave vmcnt drain orders load_lds->ds_read
        for (int k0 = 0; k0 < KD; k0 += 32) {
#pragma unroll
            for (int c = 0; c < 4; c++) gload_lds16(Ag[c] + k0, sAq + c * 512);
#pragma unroll
            for (int c = 0; c < 4; c++) gload_lds16(Bg[c] + k0, sBq + c * 512);
            wave_vmem_drain();              // wave-local; NOT a block barrier
            bf16x8 a[4], b[4];
#pragma unroll
            for (int i = 0; i < 4; i++) a[i] = *(const bf16x8*)(sAq + aOff[i]);
#pragma unroll
            for (int j = 0; j < 4; j++) b[j] = *(const bf16x8*)(sBq + bOff[j]);
#pragma unroll
            for (int i = 0; i < 4; i++)
#pragma unroll
                for (int j = 0; j < 4; j++)
                    acc[i][j] = __builtin_amdgcn_mfma_f32_16x16x32_bf16(a[i], b[j], acc[i][j], 0, 0, 0);
        }

        // epilogue (D: col=lo, row=q*4+rr)
#pragma unroll
        for (int i = 0; i < 4; i++) {
            int rowB = row0 + i * 16 + q * 4;
#pragma unroll
            for (int rr = 0; rr < 4; rr++) {
                int orow = rowB + rr;
                if (orow < n_e) {
                    if (IS_FC) {
                        size_t hrow = (size_t)(ebase + orow);
#pragma unroll
                        for (int j = 0; j < 4; j++) {
                            float v = acc[i][j][rr];
                            v = 0.5f * v * (1.f + erff(v * 0.70710678118654752f));  // exact gelu
                            hmid[hrow * ND + n0 + j * 16 + lo] = f2bf(v);
                        }
                    } else {
                        int token = lst[orow] >> 1;
                        float g = gates[e * TOKENS + orow];
#pragma unroll
                        for (int j = 0; j < 4; j++) {
                            atomicAdd(&outp[(size_t)token * ND + n0 + j * 16 + lo],
                                      acc[i][j][rr] * g);
                        }
                    }
                }
            }
        }
    }
}

// ---------------------------------------------------------------------------
extern "C" void kernel_launch(void* const* d_in, const int* in_sizes, int n_in,
                              void* d_out, int out_size, void* d_ws, size_t ws_size,
                              hipStream_t stream) {
    const float* x     = (const float*)d_in[0];   // [T, H]
    const float* gw    = (const float*)d_in[1];   // [E, H]
    const float* wfc   = (const float*)d_in[2];   // [E, FF, H]
    const float* wproj = (const float*)d_in[3];   // [E, H, FF]
    float* outp   = (float*)d_out;                       // [T*H]
    float* logits = outp + (size_t)TOKENS * HDIM;        // [T*E]

    char* ws = (char*)d_ws;
    int*   counts  = (int*)ws;                            // 8 ints
    int*   bases   = (int*)(ws + 64);                     // 8 ints
    int*   fillA   = (int*)(ws + 128);                    // 8 ints
    int*   fillB   = (int*)(ws + 192);                    // 8 ints
    int*   workA   = (int*)(ws + 256);                    // [<=3072*8] ints (worst-case skew)
    size_t off = 256 + (size_t)3072 * 8 * 4;
    int*   workB   = (int*)(ws + off); off += (size_t)1536 * 8 * 4;
    int*   entries = (int*)(ws + off);                    // [E][T]
    float* gates   = (float*)(ws + off + NEXP * TOKENS * 4);
    off += 2ull * NEXP * TOKENS * 4;
    int*   tok_e   = (int*)(ws + off);   off += (size_t)TOKENS * 2 * 4;
    float* tok_g   = (float*)(ws + off); off += (size_t)TOKENS * 2 * 4;
    unsigned short* x_bf   = (unsigned short*)(ws + off); off += (size_t)TOKENS * HDIM * 2;
    unsigned short* wfc_bf = (unsigned short*)(ws + off); off += (size_t)NEXP * FFDIM * HDIM * 2;
    unsigned short* wpj_bf = (unsigned short*)(ws + off); off += (size_t)NEXP * HDIM * FFDIM * 2;
    unsigned short* hmid   = (unsigned short*)(ws + off);        // [2T][FF] bf16, slot-compacted

    cast_bf16_2<<<2048, 256, 0, stream>>>(wfc, wfc_bf, wproj, wpj_bf,
                                          NEXP * FFDIM * HDIM / 4);
    gating<<<TOKENS / 4, 256, 0, stream>>>(x, gw, logits, tok_e, tok_g, x_bf, outp);
    build_lists<<<1, 1024, 0, stream>>>(tok_e, tok_g, counts, bases, fillA, fillB,
                                        workA, workB, entries, gates);
    moe_gemm<HDIM, FFDIM, true ><<<GEMM_GRID, 256, 0, stream>>>(
        x_bf, wfc_bf, counts, bases, fillA, workA, entries, gates, hmid, outp);
    moe_gemm<FFDIM, HDIM, false><<<GEMM_GRID, 256, 0, stream>>>(
        hmid, wpj_bf, counts, bases, fillB, workB, entries, gates, hmid, outp);
}